// Round 4
// baseline (68.605 us; speedup 1.0000x reference)
//
#include <hip/hip_runtime.h>
#include <cstdint>
#include <climits>
#include <cmath>

#define ALPHA 0.7f
#define SIGMA 0.1f
#define MIN_MINING_STEP 50

constexpr int TT    = 2048;      // sequence length (fixed by problem)
constexpr int NTH   = 512;       // threads per block
constexpr int EPT   = TT / NTH;  // 4 elements per thread
constexpr int NWAVE = NTH / 64;  // 8 waves per block

// Dual inclusive max-scan over TT elements (EPT consecutive per thread).
// v = forward lane, w = independent reversed lane. exV/exW return the
// exclusive prefix at this thread's first element. ONE internal barrier;
// caller passes a dedicated sW region (2*NWAVE ints) per call so no
// trailing barrier is needed to protect reuse.
__device__ __forceinline__ void dual_maxscan(int (&v)[EPT], int (&w)[EPT],
                                             int& exV, int& exW, int* sW) {
    const int tid = threadIdx.x, lane = tid & 63, wid = tid >> 6;
#pragma unroll
    for (int k = 1; k < EPT; ++k) {
        v[k] = max(v[k], v[k - 1]);
        w[k] = max(w[k], w[k - 1]);
    }
    int tv = v[EPT - 1], tw = w[EPT - 1];
#pragma unroll
    for (int off = 1; off < 64; off <<= 1) {
        int nv = __shfl_up(tv, off), nw = __shfl_up(tw, off);
        if (lane >= off) { tv = max(tv, nv); tw = max(tw, nw); }
    }
    if (lane == 63) { sW[wid] = tv; sW[NWAVE + wid] = tw; }
    __syncthreads();
    int ev = INT_MIN, ew = INT_MIN;
    for (int q = 0; q < wid; ++q) {
        ev = max(ev, sW[q]);
        ew = max(ew, sW[NWAVE + q]);
    }
    int uv = __shfl_up(tv, 1), uw = __shfl_up(tw, 1);
    if (lane > 0) { ev = max(ev, uv); ew = max(ew, uw); }
    exV = ev; exW = ew;
#pragma unroll
    for (int k = 0; k < EPT; ++k) {
        v[k] = max(v[k], ev);
        w[k] = max(w[k], ew);
    }
}

// Runs BEFORE the main kernel; kernel-boundary ordering makes the zero
// visible device-wide before any block's atomicAdd.
__global__ __launch_bounds__(64) void zero_out(float* __restrict__ out) {
    if (threadIdx.x == 0) out[0] = 0.0f;
}

// One block per abnormal row. sigmoid+crop-mean -> scan-based mining ->
// scan-based nearest-anchor distance -> fused splat/norm/BCE via algebraic
// split (single combined reduction) -> device-scope atomicAdd into out.
// 7 barriers total.
__global__ __launch_bounds__(NTH) void glance_fused(
    const float* __restrict__ scores,       // (B*C, T)
    const int*   __restrict__ point_label,  // (B, T)
    const int*   __restrict__ seqlen,       // (B,)
    const int*   __restrict__ step_p,       // (1,)
    float*       out,                       // (1,) pre-zeroed by zero_out
    int C, float invN)
{
    __shared__ float sS[TT];           // probs (crop-mean of sigmoids)
    __shared__ int   sM[TT];           // anchors -> mask -> (reused) bwd distance
    __shared__ int   sW[6 * NWAVE];    // 3 scan calls x (2*NWAVE) rotating regions
    __shared__ float sR[4 * NWAVE];    // final combined reduction

    const int b = blockIdx.x, tid = threadIdx.x, lane = tid & 63, wid = tid >> 6;

    const int stepv = step_p[0];
    const int vlen  = seqlen[b];

    // ---- load + sigmoid + crop mean (float4/int4 vectorized; 1 iter/thread) ----
    const float invC = 1.0f / (float)C;
    for (int q4 = tid; q4 < TT / 4; q4 += NTH) {
        float4 acc = make_float4(0.f, 0.f, 0.f, 0.f);
        for (int c = 0; c < C; ++c) {
            const float4 x = ((const float4*)(scores + ((size_t)(b * C + c)) * TT))[q4];
            acc.x += 1.0f / (1.0f + __expf(-x.x));
            acc.y += 1.0f / (1.0f + __expf(-x.y));
            acc.z += 1.0f / (1.0f + __expf(-x.z));
            acc.w += 1.0f / (1.0f + __expf(-x.w));
        }
        const int4 p = ((const int4*)(point_label + (size_t)b * TT))[q4];
        const int t = q4 * 4;
        sS[t + 0] = acc.x * invC;  sM[t + 0] = (p.x > 0) ? 1 : 0;
        sS[t + 1] = acc.y * invC;  sM[t + 1] = (p.y > 0) ? 1 : 0;
        sS[t + 2] = acc.z * invC;  sM[t + 2] = (p.z > 0) ? 1 : 0;
        sS[t + 3] = acc.w * invC;  sM[t + 3] = (p.w > 0) ? 1 : 0;
    }
    __syncthreads();                                          // B1

    const int j0 = tid * EPT;

    // ---- mining (both directions fused into dual scans) ----
    // g[j] = lastAnchorBefore(j) >= 0 && lastFail(<=j) <= lastAnchorBefore(j)
    if (stepv >= MIN_MINING_STEP) {
        // pass 1: last-anchor-index scan. v: t=j (fwd); w: t=TT-1-j (bwd coords)
        int va[EPT], wa[EPT]; int exA, exB;
#pragma unroll
        for (int k = 0; k < EPT; ++k) {
            const int j = j0 + k;
            va[k] = sM[j] ? j : -1;
            wa[k] = sM[TT - 1 - j] ? j : -1;
        }
        dual_maxscan(va, wa, exA, exB, sW);                   // B2

        // pass 2: last-fail-index scan (cond vs segment anchor, per element)
        int vf[EPT], wf[EPT]; int exF, exG;
        int qf[EPT], qb[EPT];
#pragma unroll
        for (int k = 0; k < EPT; ++k) {
            const int j  = j0 + k;
            const int qF = (k == 0) ? exA : va[k - 1];   // anchor strictly before j
            const int qB = (k == 0) ? exB : wa[k - 1];
            qf[k] = qF; qb[k] = qB;
            bool cF = false, cB = false;
            if (qF >= 0) cF = sS[j]          >= ALPHA * sS[qF];
            if (qB >= 0) cB = sS[TT - 1 - j] >= ALPHA * sS[TT - 1 - qB];
            vf[k] = cF ? -1 : j;
            wf[k] = cB ? -1 : j;
        }
        dual_maxscan(vf, wf, exF, exG, sW + 2 * NWAVE);       // B3

        // mask writes (benign same-value races; scan barrier ordered the reads)
#pragma unroll
        for (int k = 0; k < EPT; ++k) {
            const int j = j0 + k;
            const bool gF = (qf[k] >= 0) && (vf[k] <= qf[k]) && (j < vlen);
            const bool gB = (qb[k] >= 0) && (wf[k] <= qb[k]);
            if (gF) sM[j] = 1;
            if (gB) sM[TT - 1 - j] = 1;
        }
        __syncthreads();                                      // B4
    }

    // ---- nearest-mask distance via dual scan ----
    int vn[EPT], wn[EPT]; int exN, exO;
#pragma unroll
    for (int k = 0; k < EPT; ++k) {
        const int j = j0 + k;
        vn[k] = sM[j] ? j : -1;
        wn[k] = sM[TT - 1 - j] ? j : -1;
    }
    dual_maxscan(vn, wn, exN, exO, sW + 4 * NWAVE);           // B5

    // exchange bwd distance (next mask at index >= t) through sM
    // (all sM input reads happened before B5; these writes are after it)
#pragma unroll
    for (int k = 0; k < EPT; ++k) {
        const int j  = j0 + k;
        const int dB = (wn[k] >= 0) ? (j - wn[k]) : 4096;
        sM[TT - 1 - j] = dB;
    }
    __syncthreads();                                          // B6

    // any-mask: mask at <= j0 (vn[0]) OR mask at >= j0 (sM[j0] sentinel).
    // Uniform across threads by construction.
    const bool any = (vn[0] >= 0) || (sM[j0] < 4096);

    // ---- fused splat + norm + BCE, single pass ----
    // temp[i] = exp(-K*minDist^2) (per-anchor norm term m_p <= 2e-22 ignored;
    // tmax == 1 exactly when any mask exists). BCE split:
    //   per-elem = -[l1s + r*u],  u = log s - log(1-s),  r = (temp-tmn)*inv
    //   sum      = -L0 - inv*(Stu - tmn*Su)
    const float KK = 2.0f / ((float)(TT - 1) * (float)(TT - 1) * SIGMA * SIGMA);
    float tmn = INFINITY, L0 = 0.0f, Su = 0.0f, Stu = 0.0f;
#pragma unroll
    for (int k = 0; k < EPT; ++k) {
        const int j  = j0 + k;
        const int dF = (vn[k] >= 0) ? (j - vn[k]) : 4096;
        const int d  = min(dF, sM[j]);
        const float tv  = __expf(-KK * (float)(d * d));
        const float s   = sS[j];
        const float ls  = __logf(s);
        const float l1s = __logf(1.0f - s);
        const float u   = ls - l1s;
        tmn = fminf(tmn, tv);
        L0 += l1s;
        Su += u;
        Stu += tv * u;
    }
#pragma unroll
    for (int off = 32; off > 0; off >>= 1) {
        tmn = fminf(tmn, __shfl_xor(tmn, off));
        L0  += __shfl_xor(L0,  off);
        Su  += __shfl_xor(Su,  off);
        Stu += __shfl_xor(Stu, off);
    }
    if (lane == 0) {
        sR[wid * 4 + 0] = tmn;
        sR[wid * 4 + 1] = L0;
        sR[wid * 4 + 2] = Su;
        sR[wid * 4 + 3] = Stu;
    }
    __syncthreads();                                          // B7
    if (tid == 0) {
        float m = sR[0], a = sR[1], su = sR[2], st = sR[3];
        for (int w = 1; w < NWAVE; ++w) {
            m = fminf(m, sR[w * 4 + 0]);
            a  += sR[w * 4 + 1];
            su += sR[w * 4 + 2];
            st += sR[w * 4 + 3];
        }
        float loss;
        if (!any)             loss = -a;              // r = 0 everywhere
        else if (m >= 1.0f)   loss = -(su + a);       // all temp==1 -> r==1
        else {
            const float inv = 1.0f / (1.0f - m);
            loss = -a - inv * (st - m * su);
        }
        atomicAdd(out, loss * invN);   // device-scope f32 atomic
    }
}

extern "C" void kernel_launch(void* const* d_in, const int* in_sizes, int n_in,
                              void* d_out, int out_size, void* d_ws, size_t ws_size,
                              hipStream_t stream) {
    (void)n_in; (void)out_size; (void)d_ws; (void)ws_size;
    const float* scores      = (const float*)d_in[0];
    // d_in[1] = labels (unused by the reference computation)
    const int*   point_label = (const int*)d_in[2];
    const int*   seqlen      = (const int*)d_in[3];
    const int*   step_p      = (const int*)d_in[4];

    const int B  = in_sizes[1];            // labels has B elements (64)
    const int T  = in_sizes[2] / B;        // 2048 (kernel assumes TT==2048)
    const int C  = in_sizes[0] / (B * T);  // 2
    const int nb = B / 2;                  // 32

    zero_out<<<1, 64, 0, stream>>>((float*)d_out);
    glance_fused<<<nb, NTH, 0, stream>>>(scores, point_label, seqlen, step_p,
                                         (float*)d_out, C,
                                         1.0f / (float)(nb * T));
}